// Round 3
// baseline (165.918 us; speedup 1.0000x reference)
//
#include <hip/hip_runtime.h>

#define NFULL 128
#define NOUT  122
#define NBLK  768
#define NTHR  512

// ping-pong w-sums: [2][5 q][22 rows][34]
#define WROW 34
#define WQ   748          // 22*34
#define WB   3740         // 5*WQ
// ping-pong hw-sums: [2][5 q][16 rows][34]
#define HROW 34
#define HQ   544          // 16*34
#define HB   2720         // 5*HQ

// sliding 7-window over 10 values -> 4 outputs, written as 2 float2
#define EMIT4(E, OFF) {                                                   \
    float e0=E(0), e1=E(1), e2=E(2), e3=E(3), e4=E(4);                    \
    float e5=E(5), e6=E(6), e7=E(7), e8=E(8), e9=E(9);                    \
    float a = ((e0+e1)+(e2+e3)) + ((e4+e5)+e6);                           \
    float b = a + e7 - e0;                                                \
    float c = b + e8 - e1;                                                \
    float d = c + e9 - e2;                                                \
    *(float2*)(wp + (OFF))     = make_float2(a, b);                       \
    *(float2*)(wp + (OFF) + 2) = make_float2(c, d); }

__global__ __launch_bounds__(NTHR, 6)
void ssim3d_kernel(const float* __restrict__ X, const float* __restrict__ Y,
                   const float* __restrict__ DR, double* __restrict__ ws,
                   float* __restrict__ out, int mode)
{
    __shared__ __align__(16) float wbuf[2 * WB];   // 29920 B
    __shared__ __align__(16) float hbuf[2 * HB];   // 21760 B
    __shared__ float  redf[8];
    __shared__ double redd[8];
    __shared__ int lastFlag;

    const int tid = threadIdx.x;
    int bi = blockIdx.x;
    const int bb = bi & 3;  bi >>= 2;   // batch
    const int ht = bi & 7;  bi >>= 3;   // 8 h-tiles of 16
    const int wt = bi & 3;  bi >>= 2;   // 4 w-tiles (0:0-31,1:32-63,2:64-89,3:90-121)
    const int dc = bi;                  // 6 d-chunks (21,21,20,20,20,20 outputs)

    const int h0 = ht << 4;
    const int w0 = (wt == 3) ? 90 : (wt << 5);
    const int w_hi = (wt == 3) ? 122 : ((wt == 2) ? 90 : (w0 + 32));
    const int csize = (dc < 2) ? 21 : 20;
    const int d0 = (dc < 2) ? dc * 21 : 42 + (dc - 2) * 20;
    const int nsl = csize + 6;          // input slices d0 .. d0+nsl-1 (<=127)

    // SSIM constants, scaled by 343^2 (ratio-invariant)
    const float dr = DR[bb];
    const float c1s = (0.01f * dr) * (0.01f * dr) * 117649.0f;
    const float c2s = (0.03f * dr) * (0.03f * dr) * 117649.0f;
    const float tni = 1.0f / 343.0f;
    const float kkA = 2.0f * 117649.0f / 342.0f;   // A2 coeff
    const float kkB = 117649.0f / 342.0f;          // B2 coeff

    // ---- phase A: 176 tasks (22 rows x 8 quads) on tids 0..175 ----
    const int rA  = tid >> 3;           // 0..21 (valid when tid<176)
    const int qdA = tid & 7;
    int grA = h0 + rA; if (grA > NFULL - 1) grA = NFULL - 1;
    const int coffA = w0 + 4 * qdA;     // input cols coffA .. coffA+9

    // ---- phase B: 320 tasks (5 q x 2 halves x 32 cols) on tids 192..511 ----
    const int bid = tid - 192;
    const int bcB = bid & 31;
    const int bhB = (bid >> 5) & 1;     // h-half
    const int bqB = bid >> 6;           // 0..4

    // ---- phase C: 512 tasks (16 h x 32 w), one column per thread ----
    const int sC = tid & 31, hC = tid >> 5;
    const int gh = h0 + hC;
    const int gw = w0 + sC;
    const bool vld = (gh < NOUT) && (gw < w_hi);

    const size_t planeStride = (size_t)NFULL * NFULL;
    const size_t bbase = (size_t)bb * NFULL * planeStride;

    float ring[7][5];
    float run[5];
#pragma unroll
    for (int k = 0; k < 7; ++k)
#pragma unroll
        for (int q = 0; q < 5; ++q) ring[k][q] = 0.f;
#pragma unroll
    for (int q = 0; q < 5; ++q) run[q] = 0.f;
    float acc = 0.0f;

    // Pipeline with ONE barrier per slice:
    //   A(s): global -> wbuf[s&1]          (tids 0..175, loads issued first)
    //   B(s-1): wbuf[(s-1)&1] -> hbuf[(s-1)&1]   (tids 192..511)
    //   C(s-2): hbuf[s&1] -> ring/run/SSIM       (all threads)
    // All producer/consumer pairs hit different parities or are separated
    // by the barrier; single barrier per iteration is race-free.
    for (int base = 0; base <= nsl + 1; base += 7) {
#pragma unroll
        for (int u = 0; u < 7; ++u) {
            const int s = base + u;     // uniform across block
            if (s <= nsl + 1) {
                // ---- A loads: issue FIRST so C+B work hides the latency ----
                float xs[10], ys[10];
                const bool doA = (s < nsl) && (tid < 176);
                if (doA) {
                    const float* Xp = X + bbase + (size_t)(d0 + s) * planeStride
                                        + (size_t)grA * NFULL + coffA;
                    const float* Yp = Y + bbase + (size_t)(d0 + s) * planeStride
                                        + (size_t)grA * NFULL + coffA;
#pragma unroll
                    for (int k = 0; k < 5; ++k) {
                        float2 tx = *(const float2*)(Xp + 2 * k);
                        float2 ty = *(const float2*)(Yp + 2 * k);
                        xs[2 * k] = tx.x; xs[2 * k + 1] = tx.y;
                        ys[2 * k] = ty.x; ys[2 * k + 1] = ty.y;
                    }
                }
                // ---- C(s-2) ----
                if (s >= 2) {
                    const float* src = hbuf + (size_t)((s & 1) * HB) + hC * HROW + sC;
                    const int slot = (u + 5) % 7;   // (s-2)%7, static after unroll
#pragma unroll
                    for (int q = 0; q < 5; ++q) {
                        float v = src[q * HQ];
                        run[q] += v - ring[slot][q];
                        ring[slot][q] = v;
                    }
                    if (s >= 8 && vld) {
                        float Sx  = run[0];
                        float Sy  = run[1];
                        float Sxx = run[2];
                        float Syy = run[3];
                        float Sxy = run[4];
                        float P = Sx * Sy;
                        float Q = fmaf(Sx, Sx, Sy * Sy);
                        float A1 = fmaf(2.f, P, c1s);
                        float A2 = fmaf(kkA, fmaf(-tni, P, Sxy), c2s);
                        float B1 = Q + c1s;
                        float B2 = fmaf(kkB, fmaf(-tni, Q, Sxx + Syy), c2s);
                        float num = A1 * A2;
                        float den = B1 * B2;
                        float r0 = __builtin_amdgcn_rcpf(den);
                        r0 = r0 * fmaf(-den, r0, 2.0f);   // 1 Newton step
                        acc = fmaf(num, r0, acc);
                    }
                }
                // ---- B(s-1): sliding 7-window along h (half-height tasks) ----
                if (s >= 1 && s <= nsl && tid >= 192) {
                    const int p = (s - 1) & 1;
                    const float* srcw = wbuf + (size_t)(p * WB) + bqB * WQ
                                      + (bhB * 8) * WROW + bcB;
                    float* dsth = hbuf + (size_t)(p * HB) + bqB * HQ
                                      + (bhB * 8) * HROW + bcB;
                    float win = srcw[0] + srcw[WROW] + srcw[2 * WROW]
                              + srcw[3 * WROW] + srcw[4 * WROW] + srcw[5 * WROW];
#pragma unroll
                    for (int j = 0; j < 8; ++j) {
                        win += srcw[(j + 6) * WROW];
                        dsth[j * HROW] = win;
                        win -= srcw[j * WROW];
                    }
                }
                // ---- A compute: consume loads, write w-sums ----
                if (doA) {
                    float* wp = wbuf + (size_t)((s & 1) * WB) + rA * WROW + 4 * qdA;
#define EX(i)  xs[i]
#define EY(i)  ys[i]
#define EXX(i) (xs[i] * xs[i])
#define EYY(i) (ys[i] * ys[i])
#define EXY(i) (xs[i] * ys[i])
                    EMIT4(EX,  0 * WQ)
                    EMIT4(EY,  1 * WQ)
                    EMIT4(EXX, 2 * WQ)
                    EMIT4(EYY, 3 * WQ)
                    EMIT4(EXY, 4 * WQ)
#undef EX
#undef EY
#undef EXX
#undef EYY
#undef EXY
                }
                __syncthreads();
            }
        }
    }

    // ---- reduction: wave shuffle -> LDS -> per-block partial (double) ----
#pragma unroll
    for (int off = 32; off; off >>= 1) acc += __shfl_down(acc, off);
    if ((tid & 63) == 0) redf[tid >> 6] = acc;
    __syncthreads();

    if (mode) {
        if (tid == 0) {
            double t = 0.0;
#pragma unroll
            for (int i = 0; i < 8; ++i) t += (double)redf[i];
            ws[blockIdx.x] = t;
            __threadfence();
            unsigned int old = atomicAdd((unsigned int*)(ws + NBLK), 1u);
            lastFlag = (old == NBLK - 1) ? 1 : 0;
        }
        __syncthreads();
        if (lastFlag) {     // last-arriving block does the finalize
            __threadfence();
            double t = 0.0;
            for (int i = tid; i < NBLK; i += NTHR) t += ws[i];
#pragma unroll
            for (int off = 32; off; off >>= 1) t += __shfl_down(t, off);
            if ((tid & 63) == 0) redd[tid >> 6] = t;
            __syncthreads();
            if (tid == 0) {
                double r = 0.0;
#pragma unroll
                for (int i = 0; i < 8; ++i) r += redd[i];
                out[0] = (float)(r * (1.0 / 7263392.0));   // 4 * 122^3
            }
        }
    } else {
        if (tid == 0) {
            double t = 0.0;
#pragma unroll
            for (int i = 0; i < 8; ++i) t += (double)redf[i];
            atomicAdd(ws, t);
        }
    }
}

__global__ void ssim3d_finalize(const double* __restrict__ ws, float* __restrict__ out)
{
    out[0] = (float)(ws[0] * (1.0 / 7263392.0));
}

extern "C" void kernel_launch(void* const* d_in, const int* in_sizes, int n_in,
                              void* d_out, int out_size, void* d_ws, size_t ws_size,
                              hipStream_t stream)
{
    const float* X  = (const float*)d_in[0];
    const float* Y  = (const float*)d_in[1];
    const float* DR = (const float*)d_in[2];
    double* ws = (double*)d_ws;

    const int mode = (ws_size >= (size_t)(NBLK + 1) * sizeof(double)) ? 1 : 0;
    if (mode)
        hipMemsetAsync((char*)d_ws + (size_t)NBLK * sizeof(double), 0, sizeof(double), stream);
    else
        hipMemsetAsync(d_ws, 0, sizeof(double), stream);

    ssim3d_kernel<<<NBLK, NTHR, 0, stream>>>(X, Y, DR, ws, (float*)d_out, mode);
    if (!mode) ssim3d_finalize<<<1, 1, 0, stream>>>(ws, (float*)d_out);
}

// Round 4
// 162.113 us; speedup vs baseline: 1.0235x; 1.0235x over previous
//
#include <hip/hip_runtime.h>

#define NFULL 128
#define NOUT  122
#define NBLK  768
#define NTHR  256

// ping-pong staging: [2 bufs][5 quantities][22 rows][36 cols]
#define S1_R 36
#define S1_Q 792           // 22 * 36
#define S1_B 3960          // 5 * 792

// sliding 7-window over 10 values -> 4 outputs, one float4 write
#define EMIT4(E, OFF) {                                                   \
    float e0=E(0), e1=E(1), e2=E(2), e3=E(3), e4=E(4);                    \
    float e5=E(5), e6=E(6), e7=E(7), e8=E(8), e9=E(9);                    \
    float a = ((e0+e1)+(e2+e3)) + ((e4+e5)+e6);                           \
    float b = a + e7 - e0;                                                \
    float c = b + e8 - e1;                                                \
    float d = c + e9 - e2;                                                \
    *(float4*)(wp + (OFF)) = make_float4(a, b, c, d); }

__global__ __launch_bounds__(NTHR, 4)
void ssim3d_kernel(const float* __restrict__ X, const float* __restrict__ Y,
                   const float* __restrict__ DR, double* __restrict__ ws,
                   float* __restrict__ out, int mode)
{
    __shared__ __align__(16) float s1[2 * S1_B];   // 31680 B
    __shared__ float  redf[4];
    __shared__ double redd[4];
    __shared__ int lastFlag;

    const int tid = threadIdx.x;
    int bi = blockIdx.x;
    const int bb = bi & 3;  bi >>= 2;   // batch
    const int ht = bi & 7;  bi >>= 3;   // 8 h-tiles of 16
    const int wt = bi & 3;  bi >>= 2;   // 4 w-tiles (0:0-31,1:32-63,2:64-89,3:90-121)
    const int dc = bi;                  // 6 d-chunks (21,21,20,20,20,20 outputs)

    const int h0 = ht << 4;
    const int w0 = (wt == 3) ? 90 : (wt << 5);
    const int w_hi = (wt == 3) ? 122 : ((wt == 2) ? 90 : (w0 + 32));
    const int csize = (dc < 2) ? 21 : 20;
    const int d0 = (dc < 2) ? dc * 21 : 42 + (dc - 2) * 20;
    const int nsl = csize + 6;          // input slices d0 .. d0+nsl-1 (<=127)

    // SSIM constants, scaled by 343^2 (ratio-invariant)
    const float dr = DR[bb];
    const float c1s = (0.01f * dr) * (0.01f * dr) * 117649.0f;
    const float c2s = (0.03f * dr) * (0.03f * dr) * 117649.0f;
    const float tni = 1.0f / 343.0f;
    const float kkA = 2.0f * 117649.0f / 342.0f;   // A2 coeff
    const float kkB = 117649.0f / 342.0f;          // B2 coeff

    // ---- phase A mapping: 176 tasks (22 rows x 8 quads) on tids 0..175 ----
    const int rA  = tid >> 3;           // 0..21 when active
    const int qdA = tid & 7;
    const bool aAct = (tid < 176);
    int grA = h0 + rA; if (grA > NFULL - 1) grA = NFULL - 1;
    const int coffA = w0 + 4 * qdA;     // input cols coffA .. coffA+9

    // ---- phase C mapping: 16 h x 16 col-pairs, 2 output cols per thread ----
    const int sC = tid & 15, hC = tid >> 4;
    const int gh  = h0 + hC;
    const int gw0 = w0 + 2 * sC;
    const bool vh = (gh < NOUT);
    const bool vld0 = vh && (gw0 < w_hi);
    const bool vld1 = vh && (gw0 + 1 < w_hi);

    const size_t planeStride = (size_t)NFULL * NFULL;
    const size_t bbase = (size_t)bb * NFULL * planeStride;

    float2 ring[7][5];
    float2 run[5];
#pragma unroll
    for (int k = 0; k < 7; ++k)
#pragma unroll
        for (int q = 0; q < 5; ++q) ring[k][q] = make_float2(0.f, 0.f);
#pragma unroll
    for (int q = 0; q < 5; ++q) run[q] = make_float2(0.f, 0.f);
    float acc = 0.0f;

    // Per slice s (one barrier): A(s): global -> s1[s&1]  ||  C(s-1): s1[(s-1)&1]
    for (int base = 0; base <= nsl; base += 7) {
#pragma unroll
        for (int u = 0; u < 7; ++u) {
            const int s = base + u;     // uniform across block
            if (s <= nsl) {
                // ---- A(s): 10-input sliding window -> 4 w-sum cols x 5 q ----
                if (s < nsl && aAct) {
                    const float* Xp = X + bbase + (size_t)(d0 + s) * planeStride
                                        + (size_t)grA * NFULL + coffA;
                    const float* Yp = Y + bbase + (size_t)(d0 + s) * planeStride
                                        + (size_t)grA * NFULL + coffA;
                    float xs[10], ys[10];
#pragma unroll
                    for (int k = 0; k < 5; ++k) {
                        float2 tx = *(const float2*)(Xp + 2 * k);
                        float2 ty = *(const float2*)(Yp + 2 * k);
                        xs[2 * k] = tx.x; xs[2 * k + 1] = tx.y;
                        ys[2 * k] = ty.x; ys[2 * k + 1] = ty.y;
                    }
                    float* wp = s1 + (size_t)((s & 1) * S1_B) + rA * S1_R + 4 * qdA;
#define EX(i)  xs[i]
#define EY(i)  ys[i]
#define EXX(i) (xs[i] * xs[i])
#define EYY(i) (ys[i] * ys[i])
#define EXY(i) (xs[i] * ys[i])
                    EMIT4(EX,  0 * S1_Q)
                    EMIT4(EY,  1 * S1_Q)
                    EMIT4(EXX, 2 * S1_Q)
                    EMIT4(EYY, 3 * S1_Q)
                    EMIT4(EXY, 4 * S1_Q)
#undef EX
#undef EY
#undef EXX
#undef EYY
#undef EXY
                }
                // ---- C(s-1): 7-row h-sum -> d-ring -> SSIM ----
                if (s >= 1) {
                    const float* src = s1 + (size_t)(((s - 1) & 1) * S1_B)
                                          + hC * S1_R + 2 * sC;
                    const int slot = (u + 6) % 7;   // (s-1)%7, static after unroll
#pragma unroll
                    for (int q = 0; q < 5; ++q) {
                        const float* p = src + q * S1_Q;
                        float2 h = *(const float2*)p;
#pragma unroll
                        for (int r = 1; r < 7; ++r) {
                            float2 v = *(const float2*)(p + r * S1_R);
                            h.x += v.x; h.y += v.y;
                        }
                        run[q].x += h.x - ring[slot][q].x;
                        run[q].y += h.y - ring[slot][q].y;
                        ring[slot][q] = h;
                    }
                    if (s >= 7) {
#pragma unroll
                        for (int j = 0; j < 2; ++j) {
                            const bool vld = j ? vld1 : vld0;
                            if (vld) {
                                float Sx  = j ? run[0].y : run[0].x;
                                float Sy  = j ? run[1].y : run[1].x;
                                float Sxx = j ? run[2].y : run[2].x;
                                float Syy = j ? run[3].y : run[3].x;
                                float Sxy = j ? run[4].y : run[4].x;
                                float P = Sx * Sy;
                                float Q = fmaf(Sx, Sx, Sy * Sy);
                                float A1 = fmaf(2.f, P, c1s);
                                float A2 = fmaf(kkA, fmaf(-tni, P, Sxy), c2s);
                                float B1 = Q + c1s;
                                float B2 = fmaf(kkB, fmaf(-tni, Q, Sxx + Syy), c2s);
                                float num = A1 * A2;
                                float den = B1 * B2;
                                float r0 = __builtin_amdgcn_rcpf(den);
                                r0 = r0 * fmaf(-den, r0, 2.0f);   // 1 Newton step
                                acc = fmaf(num, r0, acc);
                            }
                        }
                    }
                }
                __syncthreads();
            }
        }
    }

    // ---- reduction: wave shuffle -> LDS -> per-block partial (double) ----
#pragma unroll
    for (int off = 32; off; off >>= 1) acc += __shfl_down(acc, off);
    if ((tid & 63) == 0) redf[tid >> 6] = acc;
    __syncthreads();

    if (mode) {
        if (tid == 0) {
            double t = (double)redf[0] + (double)redf[1]
                     + (double)redf[2] + (double)redf[3];
            ws[blockIdx.x] = t;
            __threadfence();
            unsigned int old = atomicAdd((unsigned int*)(ws + NBLK), 1u);
            lastFlag = (old == NBLK - 1) ? 1 : 0;
        }
        __syncthreads();
        if (lastFlag) {     // last-arriving block does the finalize
            __threadfence();
            double t = 0.0;
            for (int i = tid; i < NBLK; i += NTHR) t += ws[i];
#pragma unroll
            for (int off = 32; off; off >>= 1) t += __shfl_down(t, off);
            if ((tid & 63) == 0) redd[tid >> 6] = t;
            __syncthreads();
            if (tid == 0)
                out[0] = (float)((redd[0] + redd[1] + redd[2] + redd[3])
                                 * (1.0 / 7263392.0));   // 4 * 122^3
        }
    } else {
        if (tid == 0) {
            double t = (double)redf[0] + (double)redf[1]
                     + (double)redf[2] + (double)redf[3];
            atomicAdd(ws, t);
        }
    }
}

__global__ void ssim3d_finalize(const double* __restrict__ ws, float* __restrict__ out)
{
    out[0] = (float)(ws[0] * (1.0 / 7263392.0));
}

extern "C" void kernel_launch(void* const* d_in, const int* in_sizes, int n_in,
                              void* d_out, int out_size, void* d_ws, size_t ws_size,
                              hipStream_t stream)
{
    const float* X  = (const float*)d_in[0];
    const float* Y  = (const float*)d_in[1];
    const float* DR = (const float*)d_in[2];
    double* ws = (double*)d_ws;

    const int mode = (ws_size >= (size_t)(NBLK + 1) * sizeof(double)) ? 1 : 0;
    if (mode)
        hipMemsetAsync((char*)d_ws + (size_t)NBLK * sizeof(double), 0, sizeof(double), stream);
    else
        hipMemsetAsync(d_ws, 0, sizeof(double), stream);

    ssim3d_kernel<<<NBLK, NTHR, 0, stream>>>(X, Y, DR, ws, (float*)d_out, mode);
    if (!mode) ssim3d_finalize<<<1, 1, 0, stream>>>(ws, (float*)d_out);
}

// Round 5
// 126.714 us; speedup vs baseline: 1.3094x; 1.2794x over previous
//
#include <hip/hip_runtime.h>

#define NFULL 128
#define NOUT  122
#define NBLK  512
#define NTHR  512

// ping-pong w-sums: [2][5 q][22 rows][36]
#define WROW 36
#define WQ   792          // 22*36
#define WB   3960         // 5*WQ
// ping-pong hw-sums: [2][5 q][16 rows][34]
#define HROW 34
#define HQ   544          // 16*34
#define HB   2720         // 5*HQ

// sliding 7-window over 10 values -> 4 outputs, one b128 write
#define EMIT4(E, OFF) {                                                   \
    float e0=E(0), e1=E(1), e2=E(2), e3=E(3), e4=E(4);                    \
    float e5=E(5), e6=E(6), e7=E(7), e8=E(8), e9=E(9);                    \
    float a = ((e0+e1)+(e2+e3)) + ((e4+e5)+e6);                           \
    float b = a + e7 - e0;                                                \
    float c = b + e8 - e1;                                                \
    float d = c + e9 - e2;                                                \
    *(float4*)(wp + (OFF)) = make_float4(a, b, c, d); }

__global__ __launch_bounds__(NTHR, 4)
void ssim3d_kernel(const float* __restrict__ X, const float* __restrict__ Y,
                   const float* __restrict__ DR, double* __restrict__ ws,
                   float* __restrict__ out, int mode)
{
    __shared__ __align__(16) float wbuf[2 * WB];   // 31680 B
    __shared__ __align__(16) float hbuf[2 * HB];   // 21760 B
    __shared__ float  redf[8];
    __shared__ double redd[8];
    __shared__ int lastFlag;

    const int tid = threadIdx.x;
    int bi = blockIdx.x;
    const int bb = bi & 3;  bi >>= 2;   // batch
    const int ht = bi & 7;  bi >>= 3;   // 8 h-tiles of 16
    const int wt = bi & 3;  bi >>= 2;   // 4 w-tiles (0:0-31,1:32-63,2:64-89,3:90-121)
    const int dc = bi;                  // 4 d-chunks (31,31,30,30 outputs)

    const int h0 = ht << 4;
    const int w0 = (wt == 3) ? 90 : (wt << 5);
    const int w_hi = (wt == 3) ? 122 : ((wt == 2) ? 90 : (w0 + 32));
    const int csize = (dc < 2) ? 31 : 30;
    const int d0 = (dc < 2) ? dc * 31 : 62 + (dc - 2) * 30;
    const int nsl = csize + 6;          // input slices d0 .. d0+nsl-1 (<=127)

    // SSIM constants, scaled by 343^2 (ratio-invariant)
    const float dr = DR[bb];
    const float c1s = (0.01f * dr) * (0.01f * dr) * 117649.0f;
    const float c2s = (0.03f * dr) * (0.03f * dr) * 117649.0f;
    const float tni = 1.0f / 343.0f;
    const float kkA = 2.0f * 117649.0f / 342.0f;   // A2 coeff
    const float kkB = 117649.0f / 342.0f;          // B2 coeff

    // ---- phase A: 176 tasks (22 rows x 8 quads) on tids 0..175 ----
    const int rA  = tid >> 3;           // 0..21 (valid when tid<176)
    const int qdA = tid & 7;
    int grA = h0 + rA; if (grA > NFULL - 1) grA = NFULL - 1;
    const int coffA = w0 + 4 * qdA;     // input cols coffA .. coffA+9

    // ---- phase B: 320 tasks (5 q x 2 halves x 32 cols) on tids 192..511 ----
    const int bid = tid - 192;
    const int bcB = bid & 31;
    const int bhB = (bid >> 5) & 1;     // h-half
    const int bqB = bid >> 6;           // 0..4

    // ---- phase C: 512 tasks (16 h x 32 w), one column per thread ----
    const int sC = tid & 31, hC = tid >> 5;
    const int gh = h0 + hC;
    const int gw = w0 + sC;
    const bool vld = (gh < NOUT) && (gw < w_hi);

    const size_t planeStride = (size_t)NFULL * NFULL;
    const size_t bbase = (size_t)bb * NFULL * planeStride;

    float ring[7][5];
    float run[5];
#pragma unroll
    for (int k = 0; k < 7; ++k)
#pragma unroll
        for (int q = 0; q < 5; ++q) ring[k][q] = 0.f;
#pragma unroll
    for (int q = 0; q < 5; ++q) run[q] = 0.f;
    float acc = 0.0f;

    // Pipeline with ONE barrier per slice:
    //   A(s): global -> wbuf[s&1]                 (tids 0..175)
    //   B(s-1): wbuf[(s-1)&1] -> hbuf[(s-1)&1]    (tids 192..511)
    //   C(s-2): hbuf[s&1] -> ring/run/SSIM        (all threads)
    // Every producer/consumer pair is on different parities or separated by
    // the barrier; single barrier per iteration is race-free.
    for (int base = 0; base <= nsl + 1; base += 7) {
#pragma unroll
        for (int u = 0; u < 7; ++u) {
            const int s = base + u;     // uniform across block
            if (s <= nsl + 1) {
                // ---- A loads issued first; consumed right after C ----
                float xs[10], ys[10];
                const bool doA = (s < nsl) && (tid < 176);
                if (doA) {
                    const float* Xp = X + bbase + (size_t)(d0 + s) * planeStride
                                        + (size_t)grA * NFULL + coffA;
                    const float* Yp = Y + bbase + (size_t)(d0 + s) * planeStride
                                        + (size_t)grA * NFULL + coffA;
#pragma unroll
                    for (int k = 0; k < 5; ++k) {
                        float2 tx = *(const float2*)(Xp + 2 * k);
                        float2 ty = *(const float2*)(Yp + 2 * k);
                        xs[2 * k] = tx.x; xs[2 * k + 1] = tx.y;
                        ys[2 * k] = ty.x; ys[2 * k + 1] = ty.y;
                    }
                }
                // ---- C(s-2): 5 scalar LDS reads -> d-ring -> SSIM ----
                if (s >= 2) {
                    const float* src = hbuf + (size_t)((s & 1) * HB) + hC * HROW + sC;
                    const int slot = (u + 5) % 7;   // (s-2)%7, static after unroll
#pragma unroll
                    for (int q = 0; q < 5; ++q) {
                        float v = src[q * HQ];
                        run[q] += v - ring[slot][q];
                        ring[slot][q] = v;
                    }
                    if (s >= 8 && vld) {
                        float Sx  = run[0];
                        float Sy  = run[1];
                        float Sxx = run[2];
                        float Syy = run[3];
                        float Sxy = run[4];
                        float P = Sx * Sy;
                        float Q = fmaf(Sx, Sx, Sy * Sy);
                        float A1 = fmaf(2.f, P, c1s);
                        float A2 = fmaf(kkA, fmaf(-tni, P, Sxy), c2s);
                        float B1 = Q + c1s;
                        float B2 = fmaf(kkB, fmaf(-tni, Q, Sxx + Syy), c2s);
                        float num = A1 * A2;
                        float den = B1 * B2;
                        float r0 = __builtin_amdgcn_rcpf(den);
                        r0 = r0 * fmaf(-den, r0, 2.0f);   // 1 Newton step
                        acc = fmaf(num, r0, acc);
                    }
                }
                // ---- A compute: consume loads, write w-sums (b128) ----
                if (doA) {
                    float* wp = wbuf + (size_t)((s & 1) * WB) + rA * WROW + 4 * qdA;
#define EX(i)  xs[i]
#define EY(i)  ys[i]
#define EXX(i) (xs[i] * xs[i])
#define EYY(i) (ys[i] * ys[i])
#define EXY(i) (xs[i] * ys[i])
                    EMIT4(EX,  0 * WQ)
                    EMIT4(EY,  1 * WQ)
                    EMIT4(EXX, 2 * WQ)
                    EMIT4(EYY, 3 * WQ)
                    EMIT4(EXY, 4 * WQ)
#undef EX
#undef EY
#undef EXX
#undef EYY
#undef EXY
                }
                // ---- B(s-1): sliding 7-window along h (half-height tasks) ----
                if (s >= 1 && s <= nsl && tid >= 192) {
                    const int p = (s - 1) & 1;
                    const float* srcw = wbuf + (size_t)(p * WB) + bqB * WQ
                                      + (bhB * 8) * WROW + bcB;
                    float* dsth = hbuf + (size_t)(p * HB) + bqB * HQ
                                      + (bhB * 8) * HROW + bcB;
                    float win = srcw[0] + srcw[WROW] + srcw[2 * WROW]
                              + srcw[3 * WROW] + srcw[4 * WROW] + srcw[5 * WROW];
#pragma unroll
                    for (int j = 0; j < 8; ++j) {
                        win += srcw[(j + 6) * WROW];
                        dsth[j * HROW] = win;
                        win -= srcw[j * WROW];
                    }
                }
                __syncthreads();
            }
        }
    }

    // ---- reduction: wave shuffle -> LDS -> per-block partial (double) ----
#pragma unroll
    for (int off = 32; off; off >>= 1) acc += __shfl_down(acc, off);
    if ((tid & 63) == 0) redf[tid >> 6] = acc;
    __syncthreads();

    if (mode) {
        if (tid == 0) {
            double t = 0.0;
#pragma unroll
            for (int i = 0; i < 8; ++i) t += (double)redf[i];
            ws[blockIdx.x] = t;
            __threadfence();
            unsigned int old = atomicAdd((unsigned int*)(ws + NBLK), 1u);
            lastFlag = (old == NBLK - 1) ? 1 : 0;
        }
        __syncthreads();
        if (lastFlag) {     // last-arriving block does the finalize
            __threadfence();
            double t = 0.0;
            for (int i = tid; i < NBLK; i += NTHR) t += ws[i];
#pragma unroll
            for (int off = 32; off; off >>= 1) t += __shfl_down(t, off);
            if ((tid & 63) == 0) redd[tid >> 6] = t;
            __syncthreads();
            if (tid == 0) {
                double r = 0.0;
#pragma unroll
                for (int i = 0; i < 8; ++i) r += redd[i];
                out[0] = (float)(r * (1.0 / 7263392.0));   // 4 * 122^3
            }
        }
    } else {
        if (tid == 0) {
            double t = 0.0;
#pragma unroll
            for (int i = 0; i < 8; ++i) t += (double)redf[i];
            atomicAdd(ws, t);
        }
    }
}

__global__ void ssim3d_finalize(const double* __restrict__ ws, float* __restrict__ out)
{
    out[0] = (float)(ws[0] * (1.0 / 7263392.0));
}

extern "C" void kernel_launch(void* const* d_in, const int* in_sizes, int n_in,
                              void* d_out, int out_size, void* d_ws, size_t ws_size,
                              hipStream_t stream)
{
    const float* X  = (const float*)d_in[0];
    const float* Y  = (const float*)d_in[1];
    const float* DR = (const float*)d_in[2];
    double* ws = (double*)d_ws;

    const int mode = (ws_size >= (size_t)(NBLK + 1) * sizeof(double)) ? 1 : 0;
    if (mode)
        hipMemsetAsync((char*)d_ws + (size_t)NBLK * sizeof(double), 0, sizeof(double), stream);
    else
        hipMemsetAsync(d_ws, 0, sizeof(double), stream);

    ssim3d_kernel<<<NBLK, NTHR, 0, stream>>>(X, Y, DR, ws, (float*)d_out, mode);
    if (!mode) ssim3d_finalize<<<1, 1, 0, stream>>>(ws, (float*)d_out);
}

// Round 6
// 124.162 us; speedup vs baseline: 1.3363x; 1.0206x over previous
//
#include <hip/hip_runtime.h>

#define NFULL 128
#define NOUT  122
#define NBLK  512
#define NTHR  512

// ping-pong w-sums: [2][5 q][22 rows][36]
#define WROW 36
#define WQ   792          // 22*36
#define WB   3960         // 5*WQ
// ping-pong hw-sums: [2][5 q][16 rows][34]
#define HROW 34
#define HQ   544          // 16*34
#define HB   2720         // 5*HQ

// sliding 7-window over 10 values -> 4 outputs, one b128 write
#define EMIT4(E, OFF) {                                                   \
    float e0=E(0), e1=E(1), e2=E(2), e3=E(3), e4=E(4);                    \
    float e5=E(5), e6=E(6), e7=E(7), e8=E(8), e9=E(9);                    \
    float a = ((e0+e1)+(e2+e3)) + ((e4+e5)+e6);                           \
    float b = a + e7 - e0;                                                \
    float c = b + e8 - e1;                                                \
    float d = c + e9 - e2;                                                \
    *(float4*)(wp + (OFF)) = make_float4(a, b, c, d); }

__global__ __launch_bounds__(NTHR, 3)
void ssim3d_kernel(const float* __restrict__ X, const float* __restrict__ Y,
                   const float* __restrict__ DR, double* __restrict__ ws,
                   float* __restrict__ out, int mode)
{
    __shared__ __align__(16) float wbuf[2 * WB];   // 31680 B
    __shared__ __align__(16) float hbuf[2 * HB];   // 21760 B
    __shared__ float  redf[8];
    __shared__ double redd[8];
    __shared__ int lastFlag;

    const int tid = threadIdx.x;
    int bi = blockIdx.x;
    const int bb = bi & 3;  bi >>= 2;   // batch
    const int ht = bi & 7;  bi >>= 3;   // 8 h-tiles of 16
    const int wt = bi & 3;  bi >>= 2;   // 4 w-tiles (0:0-31,1:32-63,2:64-89,3:90-121)
    const int dc = bi;                  // 4 d-chunks (31,31,30,30 outputs)

    const int h0 = ht << 4;
    const int w0 = (wt == 3) ? 90 : (wt << 5);
    const int w_hi = (wt == 3) ? 122 : ((wt == 2) ? 90 : (w0 + 32));
    const int csize = (dc < 2) ? 31 : 30;
    const int d0 = (dc < 2) ? dc * 31 : 62 + (dc - 2) * 30;
    const int nsl = csize + 6;          // input slices d0 .. d0+nsl-1 (<=127)

    // SSIM constants, scaled by 343^2 (ratio-invariant)
    const float dr = DR[bb];
    const float c1s = (0.01f * dr) * (0.01f * dr) * 117649.0f;
    const float c2s = (0.03f * dr) * (0.03f * dr) * 117649.0f;
    const float tni = 1.0f / 343.0f;
    const float kkA = 2.0f * 117649.0f / 342.0f;   // A2 coeff
    const float kkB = 117649.0f / 342.0f;          // B2 coeff

    // ---- phase A: 176 tasks (22 rows x 8 quads) on tids 0..175 ----
    const int rA  = tid >> 3;           // 0..21 (valid when tid<176)
    const int qdA = tid & 7;
    int grA = h0 + rA; if (grA > NFULL - 1) grA = NFULL - 1;
    const int coffA = w0 + 4 * qdA;     // input cols coffA .. coffA+9

    // ---- phase B: 160 tasks (5 q x 32 cols, FULL column) on tids 192..351 ----
    const int bid = tid - 192;          // valid when 0 <= bid < 160
    const int bcB = bid & 31;
    const int bqB = bid >> 5;           // 0..4

    // ---- phase C: 512 tasks (16 h x 32 w), one column per thread ----
    const int sC = tid & 31, hC = tid >> 5;
    const int gh = h0 + hC;
    const int gw = w0 + sC;
    const bool vld = (gh < NOUT) && (gw < w_hi);

    const size_t planeStride = (size_t)NFULL * NFULL;
    const size_t bbase = (size_t)bb * NFULL * planeStride;

    float ring[7][5];
    float run[5];
#pragma unroll
    for (int k = 0; k < 7; ++k)
#pragma unroll
        for (int q = 0; q < 5; ++q) ring[k][q] = 0.f;
#pragma unroll
    for (int q = 0; q < 5; ++q) run[q] = 0.f;
    float acc = 0.0f;

    // Pipeline with ONE barrier per slice:
    //   A(s): global -> wbuf[s&1]                 (tids 0..175)
    //   B(s-1): wbuf[(s-1)&1] -> hbuf[(s-1)&1]    (tids 192..351)
    //   C(s-2): hbuf[s&1] -> ring/run/SSIM        (all threads)
    // Within-iteration order: A-loads, C, B, A-compute — so the global-load
    // latency is covered by C+B instead of C alone.
    for (int base = 0; base <= nsl + 1; base += 7) {
#pragma unroll
        for (int u = 0; u < 7; ++u) {
            const int s = base + u;     // uniform across block
            if (s <= nsl + 1) {
                // ---- A loads issued first ----
                float xs[10], ys[10];
                const bool doA = (s < nsl) && (tid < 176);
                if (doA) {
                    const float* Xp = X + bbase + (size_t)(d0 + s) * planeStride
                                        + (size_t)grA * NFULL + coffA;
                    const float* Yp = Y + bbase + (size_t)(d0 + s) * planeStride
                                        + (size_t)grA * NFULL + coffA;
#pragma unroll
                    for (int k = 0; k < 5; ++k) {
                        float2 tx = *(const float2*)(Xp + 2 * k);
                        float2 ty = *(const float2*)(Yp + 2 * k);
                        xs[2 * k] = tx.x; xs[2 * k + 1] = tx.y;
                        ys[2 * k] = ty.x; ys[2 * k + 1] = ty.y;
                    }
                }
                // ---- C(s-2): 5 scalar LDS reads -> d-ring -> SSIM ----
                if (s >= 2) {
                    const float* src = hbuf + (size_t)((s & 1) * HB) + hC * HROW + sC;
                    const int slot = (u + 5) % 7;   // (s-2)%7, static after unroll
#pragma unroll
                    for (int q = 0; q < 5; ++q) {
                        float v = src[q * HQ];
                        run[q] += v - ring[slot][q];
                        ring[slot][q] = v;
                    }
                    if (s >= 8 && vld) {
                        float Sx  = run[0];
                        float Sy  = run[1];
                        float Sxx = run[2];
                        float Syy = run[3];
                        float Sxy = run[4];
                        float P = Sx * Sy;
                        float Q = fmaf(Sx, Sx, Sy * Sy);
                        float A1 = fmaf(2.f, P, c1s);
                        float A2 = fmaf(kkA, fmaf(-tni, P, Sxy), c2s);
                        float B1 = Q + c1s;
                        float B2 = fmaf(kkB, fmaf(-tni, Q, Sxx + Syy), c2s);
                        float num = A1 * A2;
                        float den = B1 * B2;
                        float r0 = __builtin_amdgcn_rcpf(den);
                        r0 = r0 * fmaf(-den, r0, 2.0f);   // 1 Newton step
                        acc = fmaf(num, r0, acc);
                    }
                }
                // ---- B(s-1): sliding 7-window along h, full column ----
                if (s >= 1 && s <= nsl && (unsigned)bid < 160u) {
                    const int p = (s - 1) & 1;
                    const float* srcw = wbuf + (size_t)(p * WB) + bqB * WQ + bcB;
                    float* dsth = hbuf + (size_t)(p * HB) + bqB * HQ + bcB;
                    float win = srcw[0] + srcw[WROW] + srcw[2 * WROW]
                              + srcw[3 * WROW] + srcw[4 * WROW] + srcw[5 * WROW];
#pragma unroll
                    for (int j = 0; j < 16; ++j) {
                        win += srcw[(j + 6) * WROW];
                        dsth[j * HROW] = win;
                        win -= srcw[j * WROW];
                    }
                }
                // ---- A compute: consume loads, write w-sums (b128) ----
                if (doA) {
                    float* wp = wbuf + (size_t)((s & 1) * WB) + rA * WROW + 4 * qdA;
#define EX(i)  xs[i]
#define EY(i)  ys[i]
#define EXX(i) (xs[i] * xs[i])
#define EYY(i) (ys[i] * ys[i])
#define EXY(i) (xs[i] * ys[i])
                    EMIT4(EX,  0 * WQ)
                    EMIT4(EY,  1 * WQ)
                    EMIT4(EXX, 2 * WQ)
                    EMIT4(EYY, 3 * WQ)
                    EMIT4(EXY, 4 * WQ)
#undef EX
#undef EY
#undef EXX
#undef EYY
#undef EXY
                }
                __syncthreads();
            }
        }
    }

    // ---- reduction: wave shuffle -> LDS -> per-block partial (double) ----
#pragma unroll
    for (int off = 32; off; off >>= 1) acc += __shfl_down(acc, off);
    if ((tid & 63) == 0) redf[tid >> 6] = acc;
    __syncthreads();

    if (mode) {
        if (tid == 0) {
            double t = 0.0;
#pragma unroll
            for (int i = 0; i < 8; ++i) t += (double)redf[i];
            ws[blockIdx.x] = t;
            __threadfence();
            unsigned int old = atomicAdd((unsigned int*)(ws + NBLK), 1u);
            lastFlag = (old == NBLK - 1) ? 1 : 0;
        }
        __syncthreads();
        if (lastFlag) {     // last-arriving block does the finalize
            __threadfence();
            double t = 0.0;
            for (int i = tid; i < NBLK; i += NTHR) t += ws[i];
#pragma unroll
            for (int off = 32; off; off >>= 1) t += __shfl_down(t, off);
            if ((tid & 63) == 0) redd[tid >> 6] = t;
            __syncthreads();
            if (tid == 0) {
                double r = 0.0;
#pragma unroll
                for (int i = 0; i < 8; ++i) r += redd[i];
                out[0] = (float)(r * (1.0 / 7263392.0));   // 4 * 122^3
            }
        }
    } else {
        if (tid == 0) {
            double t = 0.0;
#pragma unroll
            for (int i = 0; i < 8; ++i) t += (double)redf[i];
            atomicAdd(ws, t);
        }
    }
}

__global__ void ssim3d_finalize(const double* __restrict__ ws, float* __restrict__ out)
{
    out[0] = (float)(ws[0] * (1.0 / 7263392.0));
}

extern "C" void kernel_launch(void* const* d_in, const int* in_sizes, int n_in,
                              void* d_out, int out_size, void* d_ws, size_t ws_size,
                              hipStream_t stream)
{
    const float* X  = (const float*)d_in[0];
    const float* Y  = (const float*)d_in[1];
    const float* DR = (const float*)d_in[2];
    double* ws = (double*)d_ws;

    const int mode = (ws_size >= (size_t)(NBLK + 1) * sizeof(double)) ? 1 : 0;
    if (mode)
        hipMemsetAsync((char*)d_ws + (size_t)NBLK * sizeof(double), 0, sizeof(double), stream);
    else
        hipMemsetAsync(d_ws, 0, sizeof(double), stream);

    ssim3d_kernel<<<NBLK, NTHR, 0, stream>>>(X, Y, DR, ws, (float*)d_out, mode);
    if (!mode) ssim3d_finalize<<<1, 1, 0, stream>>>(ws, (float*)d_out);
}